// Round 4
// baseline (785.776 us; speedup 1.0000x reference)
//
#include <hip/hip_runtime.h>

// Problem constants (from reference setup_inputs)
constexpr int BB = 16;      // batch
constexpr int D  = 2048;
constexpr int U  = 37;
constexpr long long DD = (long long)D * D;   // 4,194,304 elements, 16 MB

constexpr int TPB = 256;
constexpr int C   = 1024;                         // chunks; chunk = 2 matrix rows, 16 KB
constexpr int F4B = (int)(DD / 4 / C);            // 1024 float4 per chunk
constexpr int F4T = F4B / TPB;                    // 4 float4 per thread
constexpr int NGRP = 5;                           // u-groups: 8,8,8,8,5

// ws layout: partial[U][C] floats, then wdiag[U][D] floats

using f4 = __attribute__((ext_vector_type(4))) float;

__device__ __forceinline__ void load_plane(f4 (&buf)[F4T],
                                           const float* __restrict__ wplane,
                                           const long long base4) {
    const f4* __restrict__ w4 = (const f4*)wplane;
#pragma unroll
    for (int it = 0; it < F4T; ++it)
        buf[it] = __builtin_nontemporal_load(&w4[base4 + (long long)it * TPB]);
}

__device__ __forceinline__ void fma_plane(float& acc, const f4 (&m)[F4T],
                                          const f4 (&buf)[F4T]) {
#pragma unroll
    for (int it = 0; it < F4T; ++it) {
        acc = fmaf(m[it].x, buf[it].x, acc);
        acc = fmaf(m[it].y, buf[it].y, acc);
        acc = fmaf(m[it].z, buf[it].z, acc);
        acc = fmaf(m[it].w, buf[it].w, acc);
    }
}

// Block-level reduce of G per-thread accumulators into partial[u0.., c].
template<int G>
__device__ __forceinline__ void reduce_group(
    float (&acc)[G], const int u0, const int c, float* __restrict__ partial)
{
    // G independent shuffle chains -> latency hidden by ILP; once per block.
#pragma unroll
    for (int g = 0; g < G; ++g)
#pragma unroll
        for (int off = 32; off > 0; off >>= 1)
            acc[g] += __shfl_down(acc[g], off, 64);

    __shared__ float lpart[G];
    if (threadIdx.x < G) lpart[threadIdx.x] = 0.f;
    __syncthreads();
    if ((threadIdx.x & 63) == 0) {
#pragma unroll
        for (int g = 0; g < G; ++g)
            atomicAdd(&lpart[g], acc[g]);   // 4 waves x G, once per block
    }
    __syncthreads();
    if (threadIdx.x < G)
        partial[(long long)(u0 + threadIdx.x) * C + c] = lpart[threadIdx.x];
}

// 3-deep cross-plane pipeline, hand-unrolled with NAMED buffers (all indexing
// static -> registers, never scratch; r1 lesson). Load of plane g+2 is issued
// before plane g is consumed: the wave keeps ~2-3 planes (128-192 B/thread)
// in flight behind a counted vmcnt, never draining to 0 mid-stream.
__device__ __forceinline__ void stream8(
    const int u0, const int c, const long long base4,
    const f4 (&m)[F4T], const float* __restrict__ weight,
    float* __restrict__ partial)
{
    float acc[8];
#pragma unroll
    for (int g = 0; g < 8; ++g) acc[g] = 0.f;

    f4 A[F4T], B[F4T], Cb[F4T];
    load_plane(A,  weight + (long long)(u0 + 0) * DD, base4);
    load_plane(B,  weight + (long long)(u0 + 1) * DD, base4);
    load_plane(Cb, weight + (long long)(u0 + 2) * DD, base4);
    fma_plane(acc[0], m, A);
    load_plane(A,  weight + (long long)(u0 + 3) * DD, base4);
    fma_plane(acc[1], m, B);
    load_plane(B,  weight + (long long)(u0 + 4) * DD, base4);
    fma_plane(acc[2], m, Cb);
    load_plane(Cb, weight + (long long)(u0 + 5) * DD, base4);
    fma_plane(acc[3], m, A);
    load_plane(A,  weight + (long long)(u0 + 6) * DD, base4);
    fma_plane(acc[4], m, B);
    load_plane(B,  weight + (long long)(u0 + 7) * DD, base4);
    fma_plane(acc[5], m, Cb);
    fma_plane(acc[6], m, A);
    fma_plane(acc[7], m, B);

    reduce_group<8>(acc, u0, c, partial);
}

__device__ __forceinline__ void stream5(
    const int u0, const int c, const long long base4,
    const f4 (&m)[F4T], const float* __restrict__ weight,
    float* __restrict__ partial)
{
    float acc[5];
#pragma unroll
    for (int g = 0; g < 5; ++g) acc[g] = 0.f;

    f4 A[F4T], B[F4T], Cb[F4T];
    load_plane(A,  weight + (long long)(u0 + 0) * DD, base4);
    load_plane(B,  weight + (long long)(u0 + 1) * DD, base4);
    load_plane(Cb, weight + (long long)(u0 + 2) * DD, base4);
    fma_plane(acc[0], m, A);
    load_plane(A,  weight + (long long)(u0 + 3) * DD, base4);
    fma_plane(acc[1], m, B);
    load_plane(B,  weight + (long long)(u0 + 4) * DD, base4);
    fma_plane(acc[2], m, Cb);
    fma_plane(acc[3], m, A);
    fma_plane(acc[4], m, B);

    reduce_group<5>(acc, u0, c, partial);
}

// Kernel A: block (grp, c) computes partial[u, c] for u in its group.
// grp is the FAST grid dim so blocks sharing a matrix chunk are dispatched
// close together -> chunk re-reads hit L2/L3, not HBM. launch_bounds(,4)
// caps VGPR at 128 (est. use ~95) -> 4+ waves/SIMD, ~2x round-3 occupancy.
__global__ __launch_bounds__(TPB, 4) void base_kernel(
    const float* __restrict__ matrix,
    const float* __restrict__ weight,
    float* __restrict__ partial,   // (U, C)
    float* __restrict__ wdiag)     // (U, D)
{
    const int grp = blockIdx.x;
    const int c   = blockIdx.y;
    const long long base4 = (long long)c * F4B + threadIdx.x;
    const f4* __restrict__ m4 = (const f4*)matrix;

    // relu(matrix chunk) in registers: 4 x float4 = 16 VGPRs
    f4 m[F4T];
#pragma unroll
    for (int it = 0; it < F4T; ++it) {
        f4 t = m4[base4 + (long long)it * TPB];
        m[it].x = fmaxf(t.x, 0.f);
        m[it].y = fmaxf(t.y, 0.f);
        m[it].z = fmaxf(t.z, 0.f);
        m[it].w = fmaxf(t.w, 0.f);
    }

    // Diagonal extraction, group 0 only. Chunk c covers rows 2c, 2c+1.
    if (grp == 0 && threadIdx.x < 2 * U) {
        const int u = threadIdx.x >> 1;
        const int i = 2 * c + (threadIdx.x & 1);
        wdiag[u * D + i] = weight[(long long)u * DD + (long long)i * (D + 1)];
    }

    if (grp < 4) stream8(grp * 8, c, base4, m, weight, partial);
    else         stream5(32,      c, base4, m, weight, partial);
}

// Kernel B: out[b,u] = bias[u] + sum_c partial[u,c]
//                    + sum_i (relu(m_ii * x_bi) - relu(m_ii)) * wdiag[u,i]
__global__ __launch_bounds__(TPB) void finish_kernel(
    const float* __restrict__ inputs,
    const float* __restrict__ matrix,
    const float* __restrict__ bias,
    const float* __restrict__ partial,
    const float* __restrict__ wdiag,
    float* __restrict__ out)
{
    const int u = blockIdx.x;
    const int b = blockIdx.y;

    float acc = 0.f;
    for (int i = threadIdx.x; i < D; i += TPB) {
        float mm = matrix[(long long)i * (D + 1)];
        float wd = wdiag[u * D + i];
        float x  = inputs[b * D + i];
        acc += (fmaxf(mm * x, 0.f) - fmaxf(mm, 0.f)) * wd;
    }
    for (int cc = threadIdx.x; cc < C; cc += TPB)
        acc += partial[(long long)u * C + cc];

#pragma unroll
    for (int off = 32; off > 0; off >>= 1)
        acc += __shfl_down(acc, off, 64);

    __shared__ float smem[TPB / 64];
    if ((threadIdx.x & 63) == 0) smem[threadIdx.x >> 6] = acc;
    __syncthreads();
    if (threadIdx.x == 0) {
        float t = 0.f;
#pragma unroll
        for (int w = 0; w < TPB / 64; ++w) t += smem[w];
        out[b * U + u] = t + bias[u];
    }
}

extern "C" void kernel_launch(void* const* d_in, const int* in_sizes, int n_in,
                              void* d_out, int out_size, void* d_ws, size_t ws_size,
                              hipStream_t stream) {
    const float* inputs = (const float*)d_in[0];   // (B, D)
    const float* matrix = (const float*)d_in[1];   // (D, D)
    const float* weight = (const float*)d_in[2];   // (U, D, D)
    const float* bias   = (const float*)d_in[3];   // (U,)
    float* out     = (float*)d_out;                // (B, U) f32
    float* partial = (float*)d_ws;                 // (U, C)
    float* wdiag   = (float*)d_ws + (long long)U * C;  // (U, D)

    base_kernel<<<dim3(NGRP, C), TPB, 0, stream>>>(matrix, weight, partial, wdiag);
    finish_kernel<<<dim3(U, BB), TPB, 0, stream>>>(inputs, matrix, bias,
                                                   partial, wdiag, out);
}

// Round 5
// 781.089 us; speedup vs baseline: 1.0060x; 1.0060x over previous
//
#include <hip/hip_runtime.h>

// Problem constants (from reference setup_inputs)
constexpr int BB = 16;      // batch
constexpr int D  = 2048;
constexpr int U  = 37;
constexpr long long DD = (long long)D * D;   // 4,194,304 elements, 16 MB

constexpr int TPB = 256;
constexpr int C   = 512;                          // chunks; chunk = 4 matrix rows, 32 KB
constexpr int F4B = (int)(DD / 4 / C);            // 2048 float4 per chunk
constexpr int F4T = F4B / TPB;                    // 8 float4 (segments) per thread
constexpr int NGRP = 5;                           // u-groups: 8,8,8,8,5

// ws layout: partial[U][C] floats, then wdiag[U][D] floats

using f4 = __attribute__((ext_vector_type(4))) float;

// Segment-rotated nontemporal plane load: plane with rotation ROT issues its
// 8 x 4KB segments in order (ROT, ROT+1, ...) mod 8. Concurrent in-flight
// planes use different ROT -> their reads are 12KB apart instead of hitting
// identical offsets modulo the 16MB (2^24) plane stride (H4: channel aliasing).
template<int ROT>
__device__ __forceinline__ void load_plane(f4 (&buf)[F4T],
                                           const float* __restrict__ wplane,
                                           const long long chunk4) {
    const f4* __restrict__ w4 = (const f4*)wplane;
#pragma unroll
    for (int it = 0; it < F4T; ++it) {
        const int s = (it + ROT) & (F4T - 1);   // compile-time
        buf[it] = __builtin_nontemporal_load(
            &w4[chunk4 + (long long)s * TPB + threadIdx.x]);
    }
}

// buf[it] holds segment (it+ROT)&7 -> pair with m[(it+ROT)&7].
template<int ROT>
__device__ __forceinline__ void fma_plane(float& acc, const f4 (&m)[F4T],
                                          const f4 (&buf)[F4T]) {
#pragma unroll
    for (int it = 0; it < F4T; ++it) {
        const int s = (it + ROT) & (F4T - 1);
        acc = fmaf(m[s].x, buf[it].x, acc);
        acc = fmaf(m[s].y, buf[it].y, acc);
        acc = fmaf(m[s].z, buf[it].z, acc);
        acc = fmaf(m[s].w, buf[it].w, acc);
    }
}

// Block-level reduce of G per-thread accumulators into partial[u0.., cc].
template<int G>
__device__ __forceinline__ void reduce_group(
    float (&acc)[G], const int u0, const int cc, float* __restrict__ partial)
{
#pragma unroll
    for (int g = 0; g < G; ++g)
#pragma unroll
        for (int off = 32; off > 0; off >>= 1)
            acc[g] += __shfl_down(acc[g], off, 64);

    __shared__ float lpart[G];
    if (threadIdx.x < G) lpart[threadIdx.x] = 0.f;
    __syncthreads();
    if ((threadIdx.x & 63) == 0) {
#pragma unroll
        for (int g = 0; g < G; ++g)
            atomicAdd(&lpart[g], acc[g]);   // 4 waves x G, once per block
    }
    __syncthreads();
    if (threadIdx.x < G)
        partial[(long long)(u0 + threadIdx.x) * C + cc] = lpart[threadIdx.x];
}

// 2-deep cross-plane pipeline, hand-unrolled, named buffers (static indexing
// -> registers, never scratch; r1 lesson). Per-plane segment rotations
// 3g mod 8: 0,3,6,1,4,7,2,5 keep the two in-flight planes 12KB apart.
__device__ __forceinline__ void stream8(
    const int u0, const int cc, const long long chunk4,
    const f4 (&m)[F4T], const float* __restrict__ weight,
    float* __restrict__ partial)
{
    float acc[8];
#pragma unroll
    for (int g = 0; g < 8; ++g) acc[g] = 0.f;

    f4 A[F4T], B[F4T];
    load_plane<0>(A, weight + (long long)(u0 + 0) * DD, chunk4);
    load_plane<3>(B, weight + (long long)(u0 + 1) * DD, chunk4);
    fma_plane<0>(acc[0], m, A);
    load_plane<6>(A, weight + (long long)(u0 + 2) * DD, chunk4);
    fma_plane<3>(acc[1], m, B);
    load_plane<1>(B, weight + (long long)(u0 + 3) * DD, chunk4);
    fma_plane<6>(acc[2], m, A);
    load_plane<4>(A, weight + (long long)(u0 + 4) * DD, chunk4);
    fma_plane<1>(acc[3], m, B);
    load_plane<7>(B, weight + (long long)(u0 + 5) * DD, chunk4);
    fma_plane<4>(acc[4], m, A);
    load_plane<2>(A, weight + (long long)(u0 + 6) * DD, chunk4);
    fma_plane<7>(acc[5], m, B);
    load_plane<5>(B, weight + (long long)(u0 + 7) * DD, chunk4);
    fma_plane<2>(acc[6], m, A);
    fma_plane<5>(acc[7], m, B);

    reduce_group<8>(acc, u0, cc, partial);
}

__device__ __forceinline__ void stream5(
    const int u0, const int cc, const long long chunk4,
    const f4 (&m)[F4T], const float* __restrict__ weight,
    float* __restrict__ partial)
{
    float acc[5];
#pragma unroll
    for (int g = 0; g < 5; ++g) acc[g] = 0.f;

    f4 A[F4T], B[F4T];
    load_plane<0>(A, weight + (long long)(u0 + 0) * DD, chunk4);
    load_plane<3>(B, weight + (long long)(u0 + 1) * DD, chunk4);
    fma_plane<0>(acc[0], m, A);
    load_plane<6>(A, weight + (long long)(u0 + 2) * DD, chunk4);
    fma_plane<3>(acc[1], m, B);
    load_plane<1>(B, weight + (long long)(u0 + 3) * DD, chunk4);
    fma_plane<6>(acc[2], m, A);
    load_plane<4>(A, weight + (long long)(u0 + 4) * DD, chunk4);
    fma_plane<1>(acc[3], m, B);
    fma_plane<4>(acc[4], m, A);

    reduce_group<5>(acc, u0, cc, partial);
}

// Kernel A: block (grp, c) computes partial[u, cc] for its u-group, where
// cc = (c + 103*grp) mod C. The 5 concurrently-resident groups therefore
// stream DISJOINT 16MB-modulo address regions (breaking the power-of-two
// same-offset aliasing across planes). Matrix (16MB, non-nt) is fully
// L3-resident, so the lost cross-group L2 co-dispatch costs no HBM traffic.
__global__ __launch_bounds__(TPB, 2) void base_kernel(
    const float* __restrict__ matrix,
    const float* __restrict__ weight,
    float* __restrict__ partial,   // (U, C)
    float* __restrict__ wdiag)     // (U, D)
{
    const int grp = blockIdx.x;
    const int c   = blockIdx.y;
    const int cc  = (c + 103 * grp) & (C - 1);    // bijective per grp
    const long long chunk4 = (long long)cc * F4B;
    const f4* __restrict__ m4 = (const f4*)matrix;

    // relu(matrix chunk) in registers: 8 x float4 = 32 VGPRs (natural order)
    f4 m[F4T];
#pragma unroll
    for (int it = 0; it < F4T; ++it) {
        f4 t = m4[chunk4 + (long long)it * TPB + threadIdx.x];
        m[it].x = fmaxf(t.x, 0.f);
        m[it].y = fmaxf(t.y, 0.f);
        m[it].z = fmaxf(t.z, 0.f);
        m[it].w = fmaxf(t.w, 0.f);
    }

    // Diagonal extraction, group 0 only (cc == c). Chunk covers rows 4c..4c+3.
    if (grp == 0 && threadIdx.x < 4 * U) {
        const int u = threadIdx.x >> 2;
        const int i = 4 * c + (threadIdx.x & 3);
        wdiag[u * D + i] = weight[(long long)u * DD + (long long)i * (D + 1)];
    }

    if (grp < 4) stream8(grp * 8, cc, chunk4, m, weight, partial);
    else         stream5(32,      cc, chunk4, m, weight, partial);
}

// Kernel B: out[b,u] = bias[u] + sum_c partial[u,c]
//                    + sum_i (relu(m_ii * x_bi) - relu(m_ii)) * wdiag[u,i]
__global__ __launch_bounds__(TPB) void finish_kernel(
    const float* __restrict__ inputs,
    const float* __restrict__ matrix,
    const float* __restrict__ bias,
    const float* __restrict__ partial,
    const float* __restrict__ wdiag,
    float* __restrict__ out)
{
    const int u = blockIdx.x;
    const int b = blockIdx.y;

    float acc = 0.f;
    for (int i = threadIdx.x; i < D; i += TPB) {
        float mm = matrix[(long long)i * (D + 1)];
        float wd = wdiag[u * D + i];
        float x  = inputs[b * D + i];
        acc += (fmaxf(mm * x, 0.f) - fmaxf(mm, 0.f)) * wd;
    }
    for (int cc = threadIdx.x; cc < C; cc += TPB)
        acc += partial[(long long)u * C + cc];

#pragma unroll
    for (int off = 32; off > 0; off >>= 1)
        acc += __shfl_down(acc, off, 64);

    __shared__ float smem[TPB / 64];
    if ((threadIdx.x & 63) == 0) smem[threadIdx.x >> 6] = acc;
    __syncthreads();
    if (threadIdx.x == 0) {
        float t = 0.f;
#pragma unroll
        for (int w = 0; w < TPB / 64; ++w) t += smem[w];
        out[b * U + u] = t + bias[u];
    }
}

extern "C" void kernel_launch(void* const* d_in, const int* in_sizes, int n_in,
                              void* d_out, int out_size, void* d_ws, size_t ws_size,
                              hipStream_t stream) {
    const float* inputs = (const float*)d_in[0];   // (B, D)
    const float* matrix = (const float*)d_in[1];   // (D, D)
    const float* weight = (const float*)d_in[2];   // (U, D, D)
    const float* bias   = (const float*)d_in[3];   // (U,)
    float* out     = (float*)d_out;                // (B, U) f32
    float* partial = (float*)d_ws;                 // (U, C)
    float* wdiag   = (float*)d_ws + (long long)U * C;  // (U, D)

    base_kernel<<<dim3(NGRP, C), TPB, 0, stream>>>(matrix, weight, partial, wdiag);
    finish_kernel<<<dim3(U, BB), TPB, 0, stream>>>(inputs, matrix, bias,
                                                   partial, wdiag, out);
}